// Round 4
// baseline (412.768 us; speedup 1.0000x reference)
//
#include <hip/hip_runtime.h>
#include <hip/hip_bf16.h>

// SpatialAttention: B=4, H=W=64, C=D=256. N=4096 tokens/batch.
// fp32->bf16, fused QKV proj (MFMA), split-K flash attn (no-max softmax =>
// unnormalized partials just add), LDS K double-buffer via global_load_lds
// with conflict-free lane-sequential layout, combine folded into out-proj.

typedef __attribute__((ext_vector_type(8))) short short8;
typedef __attribute__((ext_vector_type(4))) short short4v;
typedef __attribute__((ext_vector_type(4))) float floatx4;

#define NB 4
#define NT 4096
#define CD 256
#define MTOT (NB * NT)   // 16384

__device__ __forceinline__ short bf16s(float f) {
    union { float f; unsigned u; } a; a.f = f;
    unsigned u = a.u;
    return (short)((u + 0x7fffu + ((u >> 16) & 1u)) >> 16);   // RNE
}

__device__ __forceinline__ float bf2f(short s) {
    union { unsigned u; float f; } a;
    a.u = ((unsigned)(unsigned short)s) << 16;
    return a.f;
}

__device__ __forceinline__ short8 ld8(const short* p) {
    return *(const short8*)p;
}

__device__ __forceinline__ floatx4 mfma16(short8 a, short8 b, floatx4 c) {
    return __builtin_amdgcn_mfma_f32_16x16x32_bf16(a, b, c, 0, 0, 0);
}

// async global->LDS DMA, 16 B/lane; LDS dest = wave-uniform base + lane*16
__device__ __forceinline__ void dma16(const void* g, void* l) {
    __builtin_amdgcn_global_load_lds(
        (const __attribute__((address_space(1))) void*)g,
        (__attribute__((address_space(3))) void*)l, 16, 0, 0);
}

// ---- convert features fp32 -> bf16 [16384 x 256] row-major ----
__global__ __launch_bounds__(256) void k_convx(const float* __restrict__ x,
                                               short* __restrict__ xb) {
    int i = (blockIdx.x * 256 + threadIdx.x) * 4;
    float4 v = *(const float4*)(x + i);
    short4v o;
    o.x = bf16s(v.x); o.y = bf16s(v.y); o.z = bf16s(v.z); o.w = bf16s(v.w);
    *(short4v*)(xb + i) = o;
}

// ---- convert + transpose weights: Wt[z][n][c] = W_z[c][n], bf16 ----
__global__ __launch_bounds__(256) void k_convw(const float* __restrict__ w0,
                                               const float* __restrict__ w1,
                                               const float* __restrict__ w2,
                                               const float* __restrict__ w3,
                                               short* __restrict__ wt) {
    int z = blockIdx.y;
    const float* w = (z == 0) ? w0 : (z == 1) ? w1 : (z == 2) ? w2 : w3;
    int c = blockIdx.x;
    int n = threadIdx.x;
    wt[z * 65536 + n * 256 + c] = bf16s(w[c * 256 + n]);
}

// ---- fused QKV projection: grid.z = 0/1/2 -> Q/K/V. one wave per 16x64 tile
__global__ __launch_bounds__(64) void k_proj3(const short* __restrict__ A,
                                              const short* __restrict__ Wt,
                                              const float* __restrict__ bq,
                                              const float* __restrict__ bk,
                                              const float* __restrict__ bv,
                                              short* __restrict__ Qb,
                                              short* __restrict__ Kb,
                                              short* __restrict__ Vt) {
    int z = blockIdx.z;
    const short* W = Wt + z * 65536;
    const float* bias = (z == 0) ? bq : (z == 1) ? bk : bv;
    float scale = (z == 0) ? 0.0625f : 1.0f;   // fold 1/sqrt(256) into Q
    int m0 = blockIdx.x * 16;
    int n0 = blockIdx.y * 64;
    int l = threadIdx.x;
    int r = l & 15, q = l >> 4;
    const short* arow = A + (size_t)(m0 + r) * CD + q * 8;
    floatx4 acc[4];
#pragma unroll
    for (int j = 0; j < 4; ++j) acc[j] = (floatx4){0.f, 0.f, 0.f, 0.f};
#pragma unroll
    for (int k0 = 0; k0 < CD; k0 += 32) {
        short8 af = ld8(arow + k0);
#pragma unroll
        for (int j = 0; j < 4; ++j)
            acc[j] = mfma16(af, ld8(W + (size_t)(n0 + j * 16 + r) * CD + q * 8 + k0), acc[j]);
    }
#pragma unroll
    for (int j = 0; j < 4; ++j) {
        int col = n0 + j * 16 + r;
        float bvv = bias[col];
#pragma unroll
        for (int i = 0; i < 4; ++i) {
            int row = m0 + q * 4 + i;
            short s = bf16s((acc[j][i] + bvv) * scale);
            if (z == 0) Qb[(size_t)row * CD + col] = s;
            else if (z == 1) Kb[(size_t)row * CD + col] = s;
            else {
                int bb = row >> 12, lm = row & (NT - 1);
                Vt[((size_t)bb * CD + col) * NT + lm] = s;
            }
        }
    }
}

// ---- split-K flash attention ----
// grid (64, NB, 2): block = 512 thr = 8 waves, BM=64 Q rows, ks-half of the
// 4096 tokens (2048 each, 32 iters of BN=64). Emits UNNORMALIZED partial O
// (bf16) + partial l (fp32); no-max softmax partials combine by addition.
// Ks LDS layout [tt][c][q][r][8]: QK frag reads are base+lane*16 (0-conflict).
__global__ __launch_bounds__(512, 4) void k_attn(const short* __restrict__ Qb,
                                                 const short* __restrict__ Kb,
                                                 const short* __restrict__ Vt,
                                                 short* __restrict__ Op0,
                                                 short* __restrict__ Op1,
                                                 float* __restrict__ Lp) {
    __shared__ __align__(16) short Ks[2][16384];   // 2 x 32 KB
    __shared__ __align__(16) short P[64][72];      // padded rows
    __shared__ float Lred[8][64];

    const int tid = threadIdx.x;
    const int w = tid >> 6;
    const int l = tid & 63;
    const int r = l & 15, q = l >> 4;
    const int b = blockIdx.y;
    const int ks = blockIdx.z;
    const int m0 = blockIdx.x * 64;
    const int t0 = ks * (NT / 2);
    const int rp = w & 1;
    const int tt = w >> 1;
    const short* Qp = Qb + (size_t)b * NT * CD;
    const short* Kp = Kb + (size_t)b * NT * CD;
    const short* Vp = Vt + (size_t)b * CD * NT;   // [256][4096]
    short* Op = ks ? Op1 : Op0;

    // DMA lane mapping: for instr (tt_d, c_d), lane l fetches
    // K[token tt_d*16 + (l&15)][chunk c_d*4 + (l>>4)] -> LDS base + l*16.
    const int tok_d = tt * 16 + r;            // tt_d = tt (w>>1)
    const int ch_base = (w & 1) * 4;          // c_d = ch_base + j

    // Q fragments (rows m0 + rp*32 + {0,16} + r), Q pre-scaled by 1/16
    short8 qf0[8], qf1[8];
#pragma unroll
    for (int c = 0; c < 8; ++c) {
        qf0[c] = ld8(Qp + (size_t)(m0 + rp * 32 + r) * CD + c * 32 + q * 8);
        qf1[c] = ld8(Qp + (size_t)(m0 + rp * 32 + 16 + r) * CD + c * 32 + q * 8);
    }

    floatx4 o[4][2];
#pragma unroll
    for (int rt = 0; rt < 4; ++rt)
#pragma unroll
        for (int dj = 0; dj < 2; ++dj) o[rt][dj] = (floatx4){0.f, 0.f, 0.f, 0.f};
    float ls0[4] = {0.f, 0.f, 0.f, 0.f}, ls1[4] = {0.f, 0.f, 0.f, 0.f};

    // prologue: DMA K tile 0 into Ks[0]
#pragma unroll
    for (int j = 0; j < 4; ++j) {
        int c_d = ch_base + j;
        dma16(Kp + (size_t)(t0 + tok_d) * CD + (c_d * 4 + (l >> 4)) * 8,
              &Ks[0][tt * 4096 + c_d * 512]);
    }

#pragma unroll 1
    for (int it = 0; it < 32; ++it) {
        const int p = it & 1;
        const int n0 = t0 + it * 64;
        __syncthreads();   // drains vmcnt(0): Ks[p] DMA complete

        // V prefetch for THIS iter
        short8 vf[4];
#pragma unroll
        for (int dj = 0; dj < 2; ++dj)
#pragma unroll
            for (int kt = 0; kt < 2; ++kt)
                vf[dj * 2 + kt] = ld8(Vp + (size_t)((2 * w + dj) * 16 + r) * NT + n0 + kt * 32 + q * 8);

        // DMA next K tile; stays in flight through compute
        if (it < 31) {
#pragma unroll
            for (int j = 0; j < 4; ++j) {
                int c_d = ch_base + j;
                dma16(Kp + (size_t)(n0 + 64 + tok_d) * CD + (c_d * 4 + (l >> 4)) * 8,
                      &Ks[1 - p][tt * 4096 + c_d * 512]);
            }
        }

        // QK: S[rows rp*32..+32][tokens tt*16..+16]; frag reads lane-sequential
        floatx4 s0 = {0.f, 0.f, 0.f, 0.f};
        floatx4 s1 = {0.f, 0.f, 0.f, 0.f};
        const short* kb = &Ks[p][tt * 4096 + l * 8];
#pragma unroll
        for (int c = 0; c < 8; ++c) {
            short8 kf = ld8(kb + c * 512);
            s0 = mfma16(qf0[c], kf, s0);
            s1 = mfma16(qf1[c], kf, s1);
        }

        // exp + P write + lsum accumulate
#pragma unroll
        for (int i = 0; i < 4; ++i) {
            float e0 = __expf(s0[i]);
            float e1 = __expf(s1[i]);
            ls0[i] += e0;
            ls1[i] += e1;
            P[rp * 32 + q * 4 + i][tt * 16 + r] = bf16s(e0);
            P[rp * 32 + 16 + q * 4 + i][tt * 16 + r] = bf16s(e1);
        }
        // P visible block-wide; NOT __syncthreads (would drain the K DMA)
        asm volatile("s_waitcnt lgkmcnt(0)\n\ts_barrier" ::: "memory");

        // PV: o[rt][dj] += P[rt rows][tok] x V[d-eighth][tok]
#pragma unroll
        for (int kt = 0; kt < 2; ++kt) {
            short8 pf[4];
#pragma unroll
            for (int rt = 0; rt < 4; ++rt)
                pf[rt] = ld8(&P[rt * 16 + r][kt * 32 + q * 8]);
#pragma unroll
            for (int rt = 0; rt < 4; ++rt)
#pragma unroll
                for (int dj = 0; dj < 2; ++dj)
                    o[rt][dj] = mfma16(pf[rt], vf[dj * 2 + kt], o[rt][dj]);
        }
    }

    // reduce lsum across r lanes, publish per-wave partials
#pragma unroll
    for (int i = 0; i < 4; ++i) {
        float s = ls0[i];
        s += __shfl_xor(s, 1); s += __shfl_xor(s, 2);
        s += __shfl_xor(s, 4); s += __shfl_xor(s, 8);
        ls0[i] = s;
        float t = ls1[i];
        t += __shfl_xor(t, 1); t += __shfl_xor(t, 2);
        t += __shfl_xor(t, 4); t += __shfl_xor(t, 8);
        ls1[i] = t;
    }
    if (r == 0) {
#pragma unroll
        for (int i = 0; i < 4; ++i) {
            Lred[w][rp * 32 + q * 4 + i] = ls0[i];
            Lred[w][rp * 32 + 16 + q * 4 + i] = ls1[i];
        }
    }
    __syncthreads();

    // partial l per row (sum over the 4 tt-waves of this rowpair)
    if (tid < 64) {
        int row = tid;
        int h = (row >> 5) & 1;
        float lt = Lred[h][row] + Lred[h + 2][row] + Lred[h + 4][row] + Lred[h + 6][row];
        Lp[(size_t)ks * MTOT + b * NT + m0 + row] = lt;
    }

    // unnormalized partial O store
#pragma unroll
    for (int rt = 0; rt < 4; ++rt) {
#pragma unroll
        for (int i = 0; i < 4; ++i) {
            int row = rt * 16 + q * 4 + i;
#pragma unroll
            for (int dj = 0; dj < 2; ++dj)
                Op[((size_t)b * NT + m0 + row) * CD + (2 * w + dj) * 16 + r] =
                    bf16s(o[rt][dj][i]);
        }
    }
}

// ---- output projection + split-K combine: A = (O0+O1)/(l0+l1), fp32 out ----
__global__ __launch_bounds__(64) void k_oproj(const short* __restrict__ Op0,
                                              const short* __restrict__ Op1,
                                              const float* __restrict__ Lp,
                                              const short* __restrict__ Wot,
                                              const float* __restrict__ bo,
                                              float* __restrict__ out) {
    int m0 = blockIdx.x * 16;
    int n0 = blockIdx.y * 64;
    int l = threadIdx.x;
    int r = l & 15, q = l >> 4;
    float inv = 1.0f / (Lp[m0 + r] + Lp[MTOT + m0 + r]);
    const short* a0row = Op0 + (size_t)(m0 + r) * CD + q * 8;
    const short* a1row = Op1 + (size_t)(m0 + r) * CD + q * 8;
    floatx4 acc[4];
#pragma unroll
    for (int j = 0; j < 4; ++j) acc[j] = (floatx4){0.f, 0.f, 0.f, 0.f};
#pragma unroll
    for (int k0 = 0; k0 < CD; k0 += 32) {
        short8 a0 = ld8(a0row + k0);
        short8 a1 = ld8(a1row + k0);
        short8 af;
#pragma unroll
        for (int j = 0; j < 8; ++j)
            af[j] = bf16s((bf2f(a0[j]) + bf2f(a1[j])) * inv);
#pragma unroll
        for (int j = 0; j < 4; ++j)
            acc[j] = mfma16(af, ld8(Wot + (size_t)(n0 + j * 16 + r) * CD + q * 8 + k0), acc[j]);
    }
#pragma unroll
    for (int j = 0; j < 4; ++j) {
        int col = n0 + j * 16 + r;
        float bvv = bo[col];
#pragma unroll
        for (int i = 0; i < 4; ++i)
            out[(size_t)(m0 + q * 4 + i) * CD + col] = acc[j][i] + bvv;
    }
}

extern "C" void kernel_launch(void* const* d_in, const int* in_sizes, int n_in,
                              void* d_out, int out_size, void* d_ws, size_t ws_size,
                              hipStream_t stream) {
    const float* x  = (const float*)d_in[0];
    const float* Wq = (const float*)d_in[1];
    const float* bq = (const float*)d_in[2];
    const float* Wk = (const float*)d_in[3];
    const float* bk = (const float*)d_in[4];
    const float* Wv = (const float*)d_in[5];
    const float* bv = (const float*)d_in[6];
    const float* Wo = (const float*)d_in[7];
    const float* bo = (const float*)d_in[8];
    float* out = (float*)d_out;

    char* ws = (char*)d_ws;
    const size_t MB = 1024u * 1024u;
    short* xb  = (short*)(ws);             // 8 MB: x bf16; DEAD after proj3 ->
    short* Op0 = (short*)(ws);             //        reused as partial-O (ks=0)
    short* Qb  = (short*)(ws + 8 * MB);    // 8 MB: Q*scale bf16
    short* Kb  = (short*)(ws + 16 * MB);   // 8 MB: K bf16
    short* Vt  = (short*)(ws + 24 * MB);   // 8 MB: V^T bf16 [4][256][4096]
    short* Op1 = (short*)(ws + 32 * MB);   // 8 MB: partial-O (ks=1)
    short* Wt  = (short*)(ws + 40 * MB);   // 512 KB: transposed weights bf16
    float* Lp  = (float*)(ws + 40 * MB + 512 * 1024);  // 128 KB: partial l [2][16384]

    k_convx<<<dim3(MTOT * CD / (256 * 4)), 256, 0, stream>>>(x, xb);
    k_convw<<<dim3(256, 4), 256, 0, stream>>>(Wq, Wk, Wv, Wo, Wt);
    k_proj3<<<dim3(MTOT / 16, CD / 64, 3), 64, 0, stream>>>(xb, Wt, bq, bk, bv, Qb, Kb, Vt);
    k_attn<<<dim3(NT / 64, NB, 2), 512, 0, stream>>>(Qb, Kb, Vt, Op0, Op1, Lp);
    k_oproj<<<dim3(MTOT / 16, CD / 64), 64, 0, stream>>>(Op0, Op1, Lp, Wt + 196608, bo, out);
}

// Round 5
// 360.295 us; speedup vs baseline: 1.1456x; 1.1456x over previous
//
#include <hip/hip_runtime.h>
#include <hip/hip_bf16.h>

// SpatialAttention: B=4, H=W=64, C=D=256. N=4096 tokens/batch.
// fp32->bf16, fused QKV proj (MFMA), split-K flash attn (no-max softmax =>
// unnormalized partials just add), LDS K double-buffer via global_load_lds
// with conflict-free lane-sequential layout, combine folded into out-proj.
// launch_bounds(512,2): round-4's (512,4) capped unified regs at 128 ->
// massive scratch spill (WRITE_SIZE 50MB). (512,2) fits in 80V+32A, no spill.

typedef __attribute__((ext_vector_type(8))) short short8;
typedef __attribute__((ext_vector_type(4))) short short4v;
typedef __attribute__((ext_vector_type(4))) float floatx4;

#define NB 4
#define NT 4096
#define CD 256
#define MTOT (NB * NT)   // 16384

__device__ __forceinline__ short bf16s(float f) {
    union { float f; unsigned u; } a; a.f = f;
    unsigned u = a.u;
    return (short)((u + 0x7fffu + ((u >> 16) & 1u)) >> 16);   // RNE
}

__device__ __forceinline__ float bf2f(short s) {
    union { unsigned u; float f; } a;
    a.u = ((unsigned)(unsigned short)s) << 16;
    return a.f;
}

__device__ __forceinline__ short8 ld8(const short* p) {
    return *(const short8*)p;
}

__device__ __forceinline__ floatx4 mfma16(short8 a, short8 b, floatx4 c) {
    return __builtin_amdgcn_mfma_f32_16x16x32_bf16(a, b, c, 0, 0, 0);
}

// async global->LDS DMA, 16 B/lane; LDS dest = wave-uniform base + lane*16
__device__ __forceinline__ void dma16(const void* g, void* l) {
    __builtin_amdgcn_global_load_lds(
        (const __attribute__((address_space(1))) void*)g,
        (__attribute__((address_space(3))) void*)l, 16, 0, 0);
}

// ---- convert features fp32 -> bf16 [16384 x 256] row-major ----
__global__ __launch_bounds__(256) void k_convx(const float* __restrict__ x,
                                               short* __restrict__ xb) {
    int i = (blockIdx.x * 256 + threadIdx.x) * 4;
    float4 v = *(const float4*)(x + i);
    short4v o;
    o.x = bf16s(v.x); o.y = bf16s(v.y); o.z = bf16s(v.z); o.w = bf16s(v.w);
    *(short4v*)(xb + i) = o;
}

// ---- convert + transpose weights: Wt[z][n][c] = W_z[c][n], bf16 ----
__global__ __launch_bounds__(256) void k_convw(const float* __restrict__ w0,
                                               const float* __restrict__ w1,
                                               const float* __restrict__ w2,
                                               const float* __restrict__ w3,
                                               short* __restrict__ wt) {
    int z = blockIdx.y;
    const float* w = (z == 0) ? w0 : (z == 1) ? w1 : (z == 2) ? w2 : w3;
    int c = blockIdx.x;
    int n = threadIdx.x;
    wt[z * 65536 + n * 256 + c] = bf16s(w[c * 256 + n]);
}

// ---- fused QKV projection: grid.z = 0/1/2 -> Q/K/V. one wave per 16x64 tile
__global__ __launch_bounds__(64) void k_proj3(const short* __restrict__ A,
                                              const short* __restrict__ Wt,
                                              const float* __restrict__ bq,
                                              const float* __restrict__ bk,
                                              const float* __restrict__ bv,
                                              short* __restrict__ Qb,
                                              short* __restrict__ Kb,
                                              short* __restrict__ Vt) {
    int z = blockIdx.z;
    const short* W = Wt + z * 65536;
    const float* bias = (z == 0) ? bq : (z == 1) ? bk : bv;
    float scale = (z == 0) ? 0.0625f : 1.0f;   // fold 1/sqrt(256) into Q
    int m0 = blockIdx.x * 16;
    int n0 = blockIdx.y * 64;
    int l = threadIdx.x;
    int r = l & 15, q = l >> 4;
    const short* arow = A + (size_t)(m0 + r) * CD + q * 8;
    floatx4 acc[4];
#pragma unroll
    for (int j = 0; j < 4; ++j) acc[j] = (floatx4){0.f, 0.f, 0.f, 0.f};
#pragma unroll
    for (int k0 = 0; k0 < CD; k0 += 32) {
        short8 af = ld8(arow + k0);
#pragma unroll
        for (int j = 0; j < 4; ++j)
            acc[j] = mfma16(af, ld8(W + (size_t)(n0 + j * 16 + r) * CD + q * 8 + k0), acc[j]);
    }
#pragma unroll
    for (int j = 0; j < 4; ++j) {
        int col = n0 + j * 16 + r;
        float bvv = bias[col];
#pragma unroll
        for (int i = 0; i < 4; ++i) {
            int row = m0 + q * 4 + i;
            short s = bf16s((acc[j][i] + bvv) * scale);
            if (z == 0) Qb[(size_t)row * CD + col] = s;
            else if (z == 1) Kb[(size_t)row * CD + col] = s;
            else {
                int bb = row >> 12, lm = row & (NT - 1);
                Vt[((size_t)bb * CD + col) * NT + lm] = s;
            }
        }
    }
}

// ---- split-K flash attention ----
// grid (64, NB, 2): block = 512 thr = 8 waves, BM=64 Q rows, ks-half of the
// 4096 tokens (2048 each, 32 iters of BN=64). Emits UNNORMALIZED partial O
// (bf16) + partial l (fp32); no-max softmax partials combine by addition.
// Ks LDS layout [tt][c][q][r][8]: QK frag reads are base+lane*16 (0-conflict).
__global__ __launch_bounds__(512, 2) void k_attn(const short* __restrict__ Qb,
                                                 const short* __restrict__ Kb,
                                                 const short* __restrict__ Vt,
                                                 short* __restrict__ Op0,
                                                 short* __restrict__ Op1,
                                                 float* __restrict__ Lp) {
    __shared__ __align__(16) short Ks[2][16384];   // 2 x 32 KB
    __shared__ __align__(16) short P[64][72];      // padded rows
    __shared__ float Lred[8][64];

    const int tid = threadIdx.x;
    const int w = tid >> 6;
    const int l = tid & 63;
    const int r = l & 15, q = l >> 4;
    const int b = blockIdx.y;
    const int ks = blockIdx.z;
    const int m0 = blockIdx.x * 64;
    const int t0 = ks * (NT / 2);
    const int rp = w & 1;
    const int tt = w >> 1;
    const short* Qp = Qb + (size_t)b * NT * CD;
    const short* Kp = Kb + (size_t)b * NT * CD;
    const short* Vp = Vt + (size_t)b * CD * NT;   // [256][4096]
    short* Op = ks ? Op1 : Op0;

    // DMA lane mapping: for instr (tt_d, c_d), lane l fetches
    // K[token tt_d*16 + (l&15)][chunk c_d*4 + (l>>4)] -> LDS base + l*16.
    const int tok_d = tt * 16 + r;            // tt_d = tt (w>>1)
    const int ch_base = (w & 1) * 4;          // c_d = ch_base + j

    // Q fragments (rows m0 + rp*32 + {0,16} + r), Q pre-scaled by 1/16
    short8 qf0[8], qf1[8];
#pragma unroll
    for (int c = 0; c < 8; ++c) {
        qf0[c] = ld8(Qp + (size_t)(m0 + rp * 32 + r) * CD + c * 32 + q * 8);
        qf1[c] = ld8(Qp + (size_t)(m0 + rp * 32 + 16 + r) * CD + c * 32 + q * 8);
    }

    floatx4 o[4][2];
#pragma unroll
    for (int rt = 0; rt < 4; ++rt)
#pragma unroll
        for (int dj = 0; dj < 2; ++dj) o[rt][dj] = (floatx4){0.f, 0.f, 0.f, 0.f};
    float ls0[4] = {0.f, 0.f, 0.f, 0.f}, ls1[4] = {0.f, 0.f, 0.f, 0.f};

    // prologue: DMA K tile 0 into Ks[0]
#pragma unroll
    for (int j = 0; j < 4; ++j) {
        int c_d = ch_base + j;
        dma16(Kp + (size_t)(t0 + tok_d) * CD + (c_d * 4 + (l >> 4)) * 8,
              &Ks[0][tt * 4096 + c_d * 512]);
    }

#pragma unroll 1
    for (int it = 0; it < 32; ++it) {
        const int p = it & 1;
        const int n0 = t0 + it * 64;
        __syncthreads();   // drains vmcnt(0): Ks[p] DMA complete

        // V prefetch for THIS iter
        short8 vf[4];
#pragma unroll
        for (int dj = 0; dj < 2; ++dj)
#pragma unroll
            for (int kt = 0; kt < 2; ++kt)
                vf[dj * 2 + kt] = ld8(Vp + (size_t)((2 * w + dj) * 16 + r) * NT + n0 + kt * 32 + q * 8);

        // DMA next K tile; stays in flight through compute
        if (it < 31) {
#pragma unroll
            for (int j = 0; j < 4; ++j) {
                int c_d = ch_base + j;
                dma16(Kp + (size_t)(n0 + 64 + tok_d) * CD + (c_d * 4 + (l >> 4)) * 8,
                      &Ks[1 - p][tt * 4096 + c_d * 512]);
            }
        }

        // QK: S[rows rp*32..+32][tokens tt*16..+16]; frag reads lane-sequential
        floatx4 s0 = {0.f, 0.f, 0.f, 0.f};
        floatx4 s1 = {0.f, 0.f, 0.f, 0.f};
        const short* kb = &Ks[p][tt * 4096 + l * 8];
#pragma unroll
        for (int c = 0; c < 8; ++c) {
            short8 kf = ld8(kb + c * 512);
            s0 = mfma16(qf0[c], kf, s0);
            s1 = mfma16(qf1[c], kf, s1);
        }

        // exp + P write + lsum accumulate
#pragma unroll
        for (int i = 0; i < 4; ++i) {
            float e0 = __expf(s0[i]);
            float e1 = __expf(s1[i]);
            ls0[i] += e0;
            ls1[i] += e1;
            P[rp * 32 + q * 4 + i][tt * 16 + r] = bf16s(e0);
            P[rp * 32 + 16 + q * 4 + i][tt * 16 + r] = bf16s(e1);
        }
        // P visible block-wide; NOT __syncthreads (would drain the K DMA)
        asm volatile("s_waitcnt lgkmcnt(0)\n\ts_barrier" ::: "memory");

        // PV: o[rt][dj] += P[rt rows][tok] x V[d-eighth][tok]
#pragma unroll
        for (int kt = 0; kt < 2; ++kt) {
            short8 pf[4];
#pragma unroll
            for (int rt = 0; rt < 4; ++rt)
                pf[rt] = ld8(&P[rt * 16 + r][kt * 32 + q * 8]);
#pragma unroll
            for (int rt = 0; rt < 4; ++rt)
#pragma unroll
                for (int dj = 0; dj < 2; ++dj)
                    o[rt][dj] = mfma16(pf[rt], vf[dj * 2 + kt], o[rt][dj]);
        }
    }

    // reduce lsum across r lanes, publish per-wave partials
#pragma unroll
    for (int i = 0; i < 4; ++i) {
        float s = ls0[i];
        s += __shfl_xor(s, 1); s += __shfl_xor(s, 2);
        s += __shfl_xor(s, 4); s += __shfl_xor(s, 8);
        ls0[i] = s;
        float t = ls1[i];
        t += __shfl_xor(t, 1); t += __shfl_xor(t, 2);
        t += __shfl_xor(t, 4); t += __shfl_xor(t, 8);
        ls1[i] = t;
    }
    if (r == 0) {
#pragma unroll
        for (int i = 0; i < 4; ++i) {
            Lred[w][rp * 32 + q * 4 + i] = ls0[i];
            Lred[w][rp * 32 + 16 + q * 4 + i] = ls1[i];
        }
    }
    __syncthreads();

    // partial l per row (sum over the 4 tt-waves of this rowpair)
    if (tid < 64) {
        int row = tid;
        int h = (row >> 5) & 1;
        float lt = Lred[h][row] + Lred[h + 2][row] + Lred[h + 4][row] + Lred[h + 6][row];
        Lp[(size_t)ks * MTOT + b * NT + m0 + row] = lt;
    }

    // unnormalized partial O store
#pragma unroll
    for (int rt = 0; rt < 4; ++rt) {
#pragma unroll
        for (int i = 0; i < 4; ++i) {
            int row = rt * 16 + q * 4 + i;
#pragma unroll
            for (int dj = 0; dj < 2; ++dj)
                Op[((size_t)b * NT + m0 + row) * CD + (2 * w + dj) * 16 + r] =
                    bf16s(o[rt][dj][i]);
        }
    }
}

// ---- output projection + split-K combine: A = (O0+O1)/(l0+l1), fp32 out ----
__global__ __launch_bounds__(64) void k_oproj(const short* __restrict__ Op0,
                                              const short* __restrict__ Op1,
                                              const float* __restrict__ Lp,
                                              const short* __restrict__ Wot,
                                              const float* __restrict__ bo,
                                              float* __restrict__ out) {
    int m0 = blockIdx.x * 16;
    int n0 = blockIdx.y * 64;
    int l = threadIdx.x;
    int r = l & 15, q = l >> 4;
    float inv = 1.0f / (Lp[m0 + r] + Lp[MTOT + m0 + r]);
    const short* a0row = Op0 + (size_t)(m0 + r) * CD + q * 8;
    const short* a1row = Op1 + (size_t)(m0 + r) * CD + q * 8;
    floatx4 acc[4];
#pragma unroll
    for (int j = 0; j < 4; ++j) acc[j] = (floatx4){0.f, 0.f, 0.f, 0.f};
#pragma unroll
    for (int k0 = 0; k0 < CD; k0 += 32) {
        short8 a0 = ld8(a0row + k0);
        short8 a1 = ld8(a1row + k0);
        short8 af;
#pragma unroll
        for (int j = 0; j < 8; ++j)
            af[j] = bf16s((bf2f(a0[j]) + bf2f(a1[j])) * inv);
#pragma unroll
        for (int j = 0; j < 4; ++j)
            acc[j] = mfma16(af, ld8(Wot + (size_t)(n0 + j * 16 + r) * CD + q * 8 + k0), acc[j]);
    }
#pragma unroll
    for (int j = 0; j < 4; ++j) {
        int col = n0 + j * 16 + r;
        float bvv = bo[col];
#pragma unroll
        for (int i = 0; i < 4; ++i)
            out[(size_t)(m0 + q * 4 + i) * CD + col] = acc[j][i] + bvv;
    }
}

extern "C" void kernel_launch(void* const* d_in, const int* in_sizes, int n_in,
                              void* d_out, int out_size, void* d_ws, size_t ws_size,
                              hipStream_t stream) {
    const float* x  = (const float*)d_in[0];
    const float* Wq = (const float*)d_in[1];
    const float* bq = (const float*)d_in[2];
    const float* Wk = (const float*)d_in[3];
    const float* bk = (const float*)d_in[4];
    const float* Wv = (const float*)d_in[5];
    const float* bv = (const float*)d_in[6];
    const float* Wo = (const float*)d_in[7];
    const float* bo = (const float*)d_in[8];
    float* out = (float*)d_out;

    char* ws = (char*)d_ws;
    const size_t MB = 1024u * 1024u;
    short* xb  = (short*)(ws);             // 8 MB: x bf16; DEAD after proj3 ->
    short* Op0 = (short*)(ws);             //        reused as partial-O (ks=0)
    short* Qb  = (short*)(ws + 8 * MB);    // 8 MB: Q*scale bf16
    short* Kb  = (short*)(ws + 16 * MB);   // 8 MB: K bf16
    short* Vt  = (short*)(ws + 24 * MB);   // 8 MB: V^T bf16 [4][256][4096]
    short* Op1 = (short*)(ws + 32 * MB);   // 8 MB: partial-O (ks=1)
    short* Wt  = (short*)(ws + 40 * MB);   // 512 KB: transposed weights bf16
    float* Lp  = (float*)(ws + 40 * MB + 512 * 1024);  // 128 KB: partial l [2][16384]

    k_convx<<<dim3(MTOT * CD / (256 * 4)), 256, 0, stream>>>(x, xb);
    k_convw<<<dim3(256, 4), 256, 0, stream>>>(Wq, Wk, Wv, Wo, Wt);
    k_proj3<<<dim3(MTOT / 16, CD / 64, 3), 64, 0, stream>>>(xb, Wt, bq, bk, bv, Qb, Kb, Vt);
    k_attn<<<dim3(NT / 64, NB, 2), 512, 0, stream>>>(Qb, Kb, Vt, Op0, Op1, Lp);
    k_oproj<<<dim3(MTOT / 16, CD / 64), 64, 0, stream>>>(Op0, Op1, Lp, Wt + 196608, bo, out);
}

// Round 6
// 336.533 us; speedup vs baseline: 1.2265x; 1.0706x over previous
//
#include <hip/hip_runtime.h>
#include <hip/hip_bf16.h>

// SpatialAttention: B=4, H=W=64, C=D=256. N=4096 tokens/batch.
// fp32->bf16, QKV proj (MFMA, W staged in LDS), split-K flash attn
// (no-max softmax => unnormalized partials add; BM=128, 8 waves, K tile
// LDS double-buffered via global_load_lds), combine folded into out-proj.
// launch_bounds(512,2): (512,4) caps regs at 128 -> scratch spill (round 4).

typedef __attribute__((ext_vector_type(8))) short short8;
typedef __attribute__((ext_vector_type(4))) short short4v;
typedef __attribute__((ext_vector_type(4))) float floatx4;

#define NB 4
#define NT 4096
#define CD 256
#define MTOT (NB * NT)   // 16384

__device__ __forceinline__ short bf16s(float f) {
    union { float f; unsigned u; } a; a.f = f;
    unsigned u = a.u;
    return (short)((u + 0x7fffu + ((u >> 16) & 1u)) >> 16);   // RNE
}

__device__ __forceinline__ float bf2f(short s) {
    union { unsigned u; float f; } a;
    a.u = ((unsigned)(unsigned short)s) << 16;
    return a.f;
}

__device__ __forceinline__ short8 ld8(const short* p) {
    return *(const short8*)p;
}

__device__ __forceinline__ floatx4 mfma16(short8 a, short8 b, floatx4 c) {
    return __builtin_amdgcn_mfma_f32_16x16x32_bf16(a, b, c, 0, 0, 0);
}

// async global->LDS DMA, 16 B/lane; LDS dest = wave-uniform base + lane*16
__device__ __forceinline__ void dma16(const void* g, void* l) {
    __builtin_amdgcn_global_load_lds(
        (const __attribute__((address_space(1))) void*)g,
        (__attribute__((address_space(3))) void*)l, 16, 0, 0);
}

// ---- convert features fp32 -> bf16 [16384 x 256] row-major ----
__global__ __launch_bounds__(256) void k_convx(const float* __restrict__ x,
                                               short* __restrict__ xb) {
    int i = (blockIdx.x * 256 + threadIdx.x) * 4;
    float4 v = *(const float4*)(x + i);
    short4v o;
    o.x = bf16s(v.x); o.y = bf16s(v.y); o.z = bf16s(v.z); o.w = bf16s(v.w);
    *(short4v*)(xb + i) = o;
}

// ---- convert + transpose weights: Wt[z][n][c] = W_z[c][n], bf16 ----
__global__ __launch_bounds__(256) void k_convw(const float* __restrict__ w0,
                                               const float* __restrict__ w1,
                                               const float* __restrict__ w2,
                                               const float* __restrict__ w3,
                                               short* __restrict__ wt) {
    int z = blockIdx.y;
    const float* w = (z == 0) ? w0 : (z == 1) ? w1 : (z == 2) ? w2 : w3;
    int c = blockIdx.x;
    int n = threadIdx.x;
    wt[z * 65536 + n * 256 + c] = bf16s(w[c * 256 + n]);
}

// ---- fused QKV projection: block = 256 thr = 4 waves, 128m x 64n tile ----
// W tile (64n x 256k = 32 KB) staged in LDS via DMA; wave w owns 32 rows.
// Ws layout [j][c][q][r][8]: frag reads are base + lane*16 (0-conflict).
__global__ __launch_bounds__(256) void k_proj3(const short* __restrict__ A,
                                               const short* __restrict__ Wt,
                                               const float* __restrict__ bq,
                                               const float* __restrict__ bk,
                                               const float* __restrict__ bv,
                                               short* __restrict__ Qb,
                                               short* __restrict__ Kb,
                                               short* __restrict__ Vt) {
    __shared__ __align__(16) short Ws[16384];
    int z = blockIdx.z;
    const short* W = Wt + z * 65536;
    const float* bias = (z == 0) ? bq : (z == 1) ? bk : bv;
    float scale = (z == 0) ? 0.0625f : 1.0f;   // fold 1/sqrt(256) into Q
    int m0 = blockIdx.x * 128;
    int n0 = blockIdx.y * 64;
    int tid = threadIdx.x;
    int w = tid >> 6, l = tid & 63, r = l & 15, q = l >> 4;

    // DMA W tile: wave w -> coltile j=w, lane l -> row n0+w*16+(l&15), chunk cg*4+(l>>4)
#pragma unroll
    for (int cg = 0; cg < 8; ++cg)
        dma16(W + (size_t)(n0 + w * 16 + r) * CD + (cg * 4 + q) * 8,
              &Ws[w * 4096 + cg * 512]);
    __syncthreads();

    const short* a0 = A + (size_t)(m0 + w * 32 + r) * CD;
    const short* a1 = a0 + 16 * CD;
    floatx4 acc[2][4];
#pragma unroll
    for (int rt = 0; rt < 2; ++rt)
#pragma unroll
        for (int j = 0; j < 4; ++j) acc[rt][j] = (floatx4){0.f, 0.f, 0.f, 0.f};
#pragma unroll
    for (int c = 0; c < 8; ++c) {
        short8 af0 = ld8(a0 + c * 32 + q * 8);
        short8 af1 = ld8(a1 + c * 32 + q * 8);
#pragma unroll
        for (int j = 0; j < 4; ++j) {
            short8 wf = ld8(&Ws[j * 4096 + c * 512 + l * 8]);
            acc[0][j] = mfma16(af0, wf, acc[0][j]);
            acc[1][j] = mfma16(af1, wf, acc[1][j]);
        }
    }
#pragma unroll
    for (int rt = 0; rt < 2; ++rt)
#pragma unroll
        for (int j = 0; j < 4; ++j) {
            int col = n0 + j * 16 + r;
            float bvv = bias[col];
#pragma unroll
            for (int i = 0; i < 4; ++i) {
                int row = m0 + w * 32 + rt * 16 + q * 4 + i;
                short s = bf16s((acc[rt][j][i] + bvv) * scale);
                if (z == 0) Qb[(size_t)row * CD + col] = s;
                else if (z == 1) Kb[(size_t)row * CD + col] = s;
                else {
                    int bb = row >> 12, lm = row & (NT - 1);
                    Vt[((size_t)bb * CD + col) * NT + lm] = s;
                }
            }
        }
}

// ---- split-K flash attention, BM=128 ----
// grid (32, NB, 2): block = 512 thr = 8 waves, 128 Q rows, half the tokens
// (2048, 32 iters of BN=64). Wave w: QK for rows w*16..+16 vs ALL 64 tokens
// (lsum fully in-wave); PV for d-cols w*32..+32, all 128 rows. Emits
// UNNORMALIZED partial O (bf16) + partial l (fp32); partials add (no-max).
__global__ __launch_bounds__(512, 2) void k_attn(const short* __restrict__ Qb,
                                                 const short* __restrict__ Kb,
                                                 const short* __restrict__ Vt,
                                                 short* __restrict__ Op0,
                                                 short* __restrict__ Op1,
                                                 float* __restrict__ Lp) {
    __shared__ __align__(16) short Ks[2][16384];   // 2 x 32 KB, [tt][c][q][r][8]
    __shared__ __align__(16) short P[128][68];     // stride 68 shorts: pf ~4-way max

    const int tid = threadIdx.x;
    const int w = tid >> 6;
    const int l = tid & 63;
    const int r = l & 15, q = l >> 4;
    const int b = blockIdx.y;
    const int ks = blockIdx.z;
    const int m0 = blockIdx.x * 128;
    const int t0 = ks * (NT / 2);
    const int tt_d = w >> 1;              // DMA token-tile
    const int cb_d = (w & 1) * 4;         // DMA chunk-group base
    const short* Qp = Qb + (size_t)b * NT * CD;
    const short* Kp = Kb + (size_t)b * NT * CD;
    const short* Vp = Vt + (size_t)b * CD * NT;   // [256][4096]
    short* Op = ks ? Op1 : Op0;

    // Q fragments: wave w owns rows m0 + w*16 .. +16 (Q pre-scaled by 1/16)
    short8 qf[8];
#pragma unroll
    for (int c = 0; c < 8; ++c)
        qf[c] = ld8(Qp + (size_t)(m0 + w * 16 + r) * CD + c * 32 + q * 8);

    floatx4 o[8][2];
#pragma unroll
    for (int rt = 0; rt < 8; ++rt)
#pragma unroll
        for (int dj = 0; dj < 2; ++dj) o[rt][dj] = (floatx4){0.f, 0.f, 0.f, 0.f};
    float ls[4] = {0.f, 0.f, 0.f, 0.f};

    // prologue: DMA K tile 0
#pragma unroll
    for (int j = 0; j < 4; ++j)
        dma16(Kp + (size_t)(t0 + tt_d * 16 + r) * CD + ((cb_d + j) * 4 + q) * 8,
              &Ks[0][tt_d * 4096 + (cb_d + j) * 512]);

#pragma unroll 1
    for (int it = 0; it < 32; ++it) {
        const int p = it & 1;
        const int n0 = t0 + it * 64;
        __syncthreads();   // drains vmcnt(0): Ks[p] DMA complete

        // V fragments for THIS iter (issued before next DMA)
        short8 vf[4];
#pragma unroll
        for (int dj = 0; dj < 2; ++dj)
#pragma unroll
            for (int kt = 0; kt < 2; ++kt)
                vf[dj * 2 + kt] = ld8(Vp + (size_t)((2 * w + dj) * 16 + r) * NT + n0 + kt * 32 + q * 8);

        // DMA next K tile; stays in flight through compute
        if (it < 31) {
#pragma unroll
            for (int j = 0; j < 4; ++j)
                dma16(Kp + (size_t)(n0 + 64 + tt_d * 16 + r) * CD + ((cb_d + j) * 4 + q) * 8,
                      &Ks[1 - p][tt_d * 4096 + (cb_d + j) * 512]);
        }

        // QK: S[16 rows][64 tokens], 32 MFMA, frag reads lane-sequential
        floatx4 s[4];
#pragma unroll
        for (int tt = 0; tt < 4; ++tt) s[tt] = (floatx4){0.f, 0.f, 0.f, 0.f};
        const short* kb = &Ks[p][l * 8];
#pragma unroll
        for (int c = 0; c < 8; ++c)
#pragma unroll
            for (int tt = 0; tt < 4; ++tt)
                s[tt] = mfma16(qf[c], ld8(kb + tt * 4096 + c * 512), s[tt]);

        // exp + P write + in-wave lsum
#pragma unroll
        for (int tt = 0; tt < 4; ++tt)
#pragma unroll
            for (int i = 0; i < 4; ++i) {
                float e = __expf(s[tt][i]);
                ls[i] += e;
                P[w * 16 + q * 4 + i][tt * 16 + r] = bf16s(e);
            }
        // P visible block-wide; NOT __syncthreads (would drain the K DMA)
        asm volatile("s_waitcnt lgkmcnt(0)\n\ts_barrier" ::: "memory");

        // PV: o[rt][dj] += P[rt rows] x V[d-slice], 32 MFMA
#pragma unroll
        for (int kt = 0; kt < 2; ++kt)
#pragma unroll
            for (int rt = 0; rt < 8; ++rt) {
                short8 pf = ld8(&P[rt * 16 + r][kt * 32 + q * 8]);
                o[rt][0] = mfma16(pf, vf[kt], o[rt][0]);
                o[rt][1] = mfma16(pf, vf[2 + kt], o[rt][1]);
            }
    }

    // partial lsum: reduce over r lanes (row = w*16 + q*4 + i, fully in-wave)
#pragma unroll
    for (int i = 0; i < 4; ++i) {
        float s = ls[i];
        s += __shfl_xor(s, 1); s += __shfl_xor(s, 2);
        s += __shfl_xor(s, 4); s += __shfl_xor(s, 8);
        ls[i] = s;
    }
    if (r == 0) {
#pragma unroll
        for (int i = 0; i < 4; ++i)
            Lp[(size_t)ks * MTOT + b * NT + m0 + w * 16 + q * 4 + i] = ls[i];
    }

    // unnormalized partial O store (cols w*32..+32, all 128 rows)
#pragma unroll
    for (int rt = 0; rt < 8; ++rt)
#pragma unroll
        for (int i = 0; i < 4; ++i) {
            int row = m0 + rt * 16 + q * 4 + i;
#pragma unroll
            for (int dj = 0; dj < 2; ++dj)
                Op[((size_t)b * NT + row) * CD + w * 32 + dj * 16 + r] =
                    bf16s(o[rt][dj][i]);
        }
}

// ---- output projection + split-K combine: A = (O0+O1)/(l0+l1), fp32 out ----
// same 128x64 block structure as k_proj3, W in LDS.
__global__ __launch_bounds__(256) void k_oproj(const short* __restrict__ Op0,
                                               const short* __restrict__ Op1,
                                               const float* __restrict__ Lp,
                                               const short* __restrict__ Wot,
                                               const float* __restrict__ bo,
                                               float* __restrict__ out) {
    __shared__ __align__(16) short Ws[16384];
    int m0 = blockIdx.x * 128;
    int n0 = blockIdx.y * 64;
    int tid = threadIdx.x;
    int w = tid >> 6, l = tid & 63, r = l & 15, q = l >> 4;

#pragma unroll
    for (int cg = 0; cg < 8; ++cg)
        dma16(Wot + (size_t)(n0 + w * 16 + r) * CD + (cg * 4 + q) * 8,
              &Ws[w * 4096 + cg * 512]);
    __syncthreads();

    int row0 = m0 + w * 32 + r;
    float inv0 = 1.0f / (Lp[row0] + Lp[MTOT + row0]);
    float inv1 = 1.0f / (Lp[row0 + 16] + Lp[MTOT + row0 + 16]);
    const short* p00 = Op0 + (size_t)row0 * CD;
    const short* p01 = Op1 + (size_t)row0 * CD;
    floatx4 acc[2][4];
#pragma unroll
    for (int rt = 0; rt < 2; ++rt)
#pragma unroll
        for (int j = 0; j < 4; ++j) acc[rt][j] = (floatx4){0.f, 0.f, 0.f, 0.f};
#pragma unroll
    for (int c = 0; c < 8; ++c) {
        short8 x0 = ld8(p00 + c * 32 + q * 8);
        short8 y0 = ld8(p01 + c * 32 + q * 8);
        short8 x1 = ld8(p00 + 16 * CD + c * 32 + q * 8);
        short8 y1 = ld8(p01 + 16 * CD + c * 32 + q * 8);
        short8 af0, af1;
#pragma unroll
        for (int jj = 0; jj < 8; ++jj) {
            af0[jj] = bf16s((bf2f(x0[jj]) + bf2f(y0[jj])) * inv0);
            af1[jj] = bf16s((bf2f(x1[jj]) + bf2f(y1[jj])) * inv1);
        }
#pragma unroll
        for (int j = 0; j < 4; ++j) {
            short8 wf = ld8(&Ws[j * 4096 + c * 512 + l * 8]);
            acc[0][j] = mfma16(af0, wf, acc[0][j]);
            acc[1][j] = mfma16(af1, wf, acc[1][j]);
        }
    }
#pragma unroll
    for (int rt = 0; rt < 2; ++rt)
#pragma unroll
        for (int j = 0; j < 4; ++j) {
            int col = n0 + j * 16 + r;
            float bvv = bo[col];
#pragma unroll
            for (int i = 0; i < 4; ++i)
                out[(size_t)(m0 + w * 32 + rt * 16 + q * 4 + i) * CD + col] =
                    acc[rt][j][i] + bvv;
        }
}

extern "C" void kernel_launch(void* const* d_in, const int* in_sizes, int n_in,
                              void* d_out, int out_size, void* d_ws, size_t ws_size,
                              hipStream_t stream) {
    const float* x  = (const float*)d_in[0];
    const float* Wq = (const float*)d_in[1];
    const float* bq = (const float*)d_in[2];
    const float* Wk = (const float*)d_in[3];
    const float* bk = (const float*)d_in[4];
    const float* Wv = (const float*)d_in[5];
    const float* bv = (const float*)d_in[6];
    const float* Wo = (const float*)d_in[7];
    const float* bo = (const float*)d_in[8];
    float* out = (float*)d_out;

    char* ws = (char*)d_ws;
    const size_t MB = 1024u * 1024u;
    short* xb  = (short*)(ws);             // 8 MB: x bf16; DEAD after proj3 ->
    short* Op0 = (short*)(ws);             //        reused as partial-O (ks=0)
    short* Qb  = (short*)(ws + 8 * MB);    // 8 MB: Q*scale bf16
    short* Kb  = (short*)(ws + 16 * MB);   // 8 MB: K bf16
    short* Vt  = (short*)(ws + 24 * MB);   // 8 MB: V^T bf16 [4][256][4096]
    short* Op1 = (short*)(ws + 32 * MB);   // 8 MB: partial-O (ks=1)
    short* Wt  = (short*)(ws + 40 * MB);   // 512 KB: transposed weights bf16
    float* Lp  = (float*)(ws + 40 * MB + 512 * 1024);  // 128 KB: partial l [2][16384]

    k_convx<<<dim3(MTOT * CD / (256 * 4)), 256, 0, stream>>>(x, xb);
    k_convw<<<dim3(256, 4), 256, 0, stream>>>(Wq, Wk, Wv, Wo, Wt);
    k_proj3<<<dim3(MTOT / 128, CD / 64, 3), 256, 0, stream>>>(xb, Wt, bq, bk, bv, Qb, Kb, Vt);
    k_attn<<<dim3(NT / 128, NB, 2), 512, 0, stream>>>(Qb, Kb, Vt, Op0, Op1, Lp);
    k_oproj<<<dim3(MTOT / 128, CD / 64), 256, 0, stream>>>(Op0, Op1, Lp, Wt + 196608, bo, out);
}

// Round 7
// 258.227 us; speedup vs baseline: 1.5985x; 1.3032x over previous
//
#include <hip/hip_runtime.h>
#include <hip/hip_bf16.h>

// SpatialAttention: B=4, H=W=64, C=D=256. N=4096 tokens/batch.
// fp32->bf16, QKV proj (MFMA, W staged in LDS), split-K flash attn with
// SWAPPED QK (S^T in C-layout -> packed b64 P writes, scalar lsum), lean
// 4-wave blocks (BM=64, BN=32, ~37 KB LDS, launch_bounds(256,3)) for
// 3 blocks/CU, K-tile LDS double-buffered via global_load_lds. No-max
// softmax => unnormalized partials add; combine folded into out-proj.

typedef __attribute__((ext_vector_type(8))) short short8;
typedef __attribute__((ext_vector_type(4))) short short4v;
typedef __attribute__((ext_vector_type(4))) float floatx4;

#define NB 4
#define NT 4096
#define CD 256
#define MTOT (NB * NT)   // 16384

__device__ __forceinline__ short bf16s(float f) {
    union { float f; unsigned u; } a; a.f = f;
    unsigned u = a.u;
    return (short)((u + 0x7fffu + ((u >> 16) & 1u)) >> 16);   // RNE
}

__device__ __forceinline__ float bf2f(short s) {
    union { unsigned u; float f; } a;
    a.u = ((unsigned)(unsigned short)s) << 16;
    return a.f;
}

__device__ __forceinline__ short8 ld8(const short* p) {
    return *(const short8*)p;
}

__device__ __forceinline__ floatx4 mfma16(short8 a, short8 b, floatx4 c) {
    return __builtin_amdgcn_mfma_f32_16x16x32_bf16(a, b, c, 0, 0, 0);
}

// async global->LDS DMA, 16 B/lane; LDS dest = wave-uniform base + lane*16
__device__ __forceinline__ void dma16(const void* g, void* l) {
    __builtin_amdgcn_global_load_lds(
        (const __attribute__((address_space(1))) void*)g,
        (__attribute__((address_space(3))) void*)l, 16, 0, 0);
}

// ---- convert features fp32 -> bf16 [16384 x 256] row-major ----
__global__ __launch_bounds__(256) void k_convx(const float* __restrict__ x,
                                               short* __restrict__ xb) {
    int i = (blockIdx.x * 256 + threadIdx.x) * 4;
    float4 v = *(const float4*)(x + i);
    short4v o;
    o.x = bf16s(v.x); o.y = bf16s(v.y); o.z = bf16s(v.z); o.w = bf16s(v.w);
    *(short4v*)(xb + i) = o;
}

// ---- convert + transpose weights: Wt[z][n][c] = W_z[c][n], bf16 ----
__global__ __launch_bounds__(256) void k_convw(const float* __restrict__ w0,
                                               const float* __restrict__ w1,
                                               const float* __restrict__ w2,
                                               const float* __restrict__ w3,
                                               short* __restrict__ wt) {
    int z = blockIdx.y;
    const float* w = (z == 0) ? w0 : (z == 1) ? w1 : (z == 2) ? w2 : w3;
    int c = blockIdx.x;
    int n = threadIdx.x;
    wt[z * 65536 + n * 256 + c] = bf16s(w[c * 256 + n]);
}

// ---- fused QKV projection: block = 256 thr = 4 waves, 128m x 64n tile ----
__global__ __launch_bounds__(256) void k_proj3(const short* __restrict__ A,
                                               const short* __restrict__ Wt,
                                               const float* __restrict__ bq,
                                               const float* __restrict__ bk,
                                               const float* __restrict__ bv,
                                               short* __restrict__ Qb,
                                               short* __restrict__ Kb,
                                               short* __restrict__ Vt) {
    __shared__ __align__(16) short Ws[16384];
    int z = blockIdx.z;
    const short* W = Wt + z * 65536;
    const float* bias = (z == 0) ? bq : (z == 1) ? bk : bv;
    float scale = (z == 0) ? 0.0625f : 1.0f;   // fold 1/sqrt(256) into Q
    int m0 = blockIdx.x * 128;
    int n0 = blockIdx.y * 64;
    int tid = threadIdx.x;
    int w = tid >> 6, l = tid & 63, r = l & 15, q = l >> 4;

#pragma unroll
    for (int cg = 0; cg < 8; ++cg)
        dma16(W + (size_t)(n0 + w * 16 + r) * CD + (cg * 4 + q) * 8,
              &Ws[w * 4096 + cg * 512]);
    __syncthreads();

    const short* a0 = A + (size_t)(m0 + w * 32 + r) * CD;
    const short* a1 = a0 + 16 * CD;
    floatx4 acc[2][4];
#pragma unroll
    for (int rt = 0; rt < 2; ++rt)
#pragma unroll
        for (int j = 0; j < 4; ++j) acc[rt][j] = (floatx4){0.f, 0.f, 0.f, 0.f};
#pragma unroll
    for (int c = 0; c < 8; ++c) {
        short8 af0 = ld8(a0 + c * 32 + q * 8);
        short8 af1 = ld8(a1 + c * 32 + q * 8);
#pragma unroll
        for (int j = 0; j < 4; ++j) {
            short8 wf = ld8(&Ws[j * 4096 + c * 512 + l * 8]);
            acc[0][j] = mfma16(af0, wf, acc[0][j]);
            acc[1][j] = mfma16(af1, wf, acc[1][j]);
        }
    }
#pragma unroll
    for (int rt = 0; rt < 2; ++rt)
#pragma unroll
        for (int j = 0; j < 4; ++j) {
            int col = n0 + j * 16 + r;
            float bvv = bias[col];
#pragma unroll
            for (int i = 0; i < 4; ++i) {
                int row = m0 + w * 32 + rt * 16 + q * 4 + i;
                short s = bf16s((acc[rt][j][i] + bvv) * scale);
                if (z == 0) Qb[(size_t)row * CD + col] = s;
                else if (z == 1) Kb[(size_t)row * CD + col] = s;
                else {
                    int bb = row >> 12, lm = row & (NT - 1);
                    Vt[((size_t)bb * CD + col) * NT + lm] = s;
                }
            }
        }
}

// ---- split-K flash attention, BM=64, BN=32, 4 waves ----
// grid (64, NB, nks). Wave w: QK-swap for rows m0+w*16..+16 vs 32 tokens
// (S^T in regs -> exp -> packed b64 P write), PV for d-cols w*64..+64,
// all 64 rows. Ks [tt][c][lane*8] dbuf via DMA. Partials: O bf16 + l fp32.
__global__ __launch_bounds__(256, 3) void k_attn(const short* __restrict__ Qb,
                                                 const short* __restrict__ Kb,
                                                 const short* __restrict__ Vt,
                                                 short* __restrict__ Op0,
                                                 short* __restrict__ Op1,
                                                 short* __restrict__ Op2,
                                                 float* __restrict__ Lp,
                                                 int nks) {
    __shared__ __align__(16) short Ks[2][8192];   // 2 x 16 KB
    __shared__ __align__(16) short P[64][36];     // [row][tok], pad 4

    const int tid = threadIdx.x;
    const int w = tid >> 6;
    const int l = tid & 63;
    const int r = l & 15, q = l >> 4;
    const int b = blockIdx.y;
    const int ks = blockIdx.z;
    const int m0 = blockIdx.x * 64;
    // token range: 128 units of 32 tokens split across nks
    const int qq = 128 / nks, rem = 128 % nks;
    const int u0 = ks * qq + (ks < rem ? ks : rem);
    const int cnt = qq + (ks < rem ? 1 : 0);
    const int t0 = u0 * 32;
    const int tt_d = w & 1;               // DMA token-subtile
    const int cb_d = (w >> 1) * 4;        // DMA chunk-group base
    const short* Qp = Qb + (size_t)b * NT * CD;
    const short* Kp = Kb + (size_t)b * NT * CD;
    const short* Vp = Vt + (size_t)b * CD * NT;   // [256][4096]
    short* Op = (ks == 0) ? Op0 : (ks == 1) ? Op1 : Op2;

    // Q fragments (B-operand): rows m0 + w*16 + r, Q pre-scaled by 1/16
    short8 qf[8];
#pragma unroll
    for (int c = 0; c < 8; ++c)
        qf[c] = ld8(Qp + (size_t)(m0 + w * 16 + r) * CD + c * 32 + q * 8);

    floatx4 o[4][4];
#pragma unroll
    for (int rt = 0; rt < 4; ++rt)
#pragma unroll
        for (int dt = 0; dt < 4; ++dt) o[rt][dt] = (floatx4){0.f, 0.f, 0.f, 0.f};
    float ls = 0.f;

    // prologue: DMA K tile 0 into Ks[0]
#pragma unroll
    for (int j = 0; j < 4; ++j)
        dma16(Kp + (size_t)(t0 + tt_d * 16 + r) * CD + ((cb_d + j) * 4 + q) * 8,
              &Ks[0][tt_d * 4096 + (cb_d + j) * 512]);

#pragma unroll 1
    for (int it = 0; it < cnt; ++it) {
        const int p = it & 1;
        const int n0 = t0 + it * 32;
        __syncthreads();   // drains vmcnt(0): Ks[p] DMA complete, P consumed

        // V fragments for THIS iter (before next DMA so their wait leaves DMA in flight)
        short8 vf[4];
#pragma unroll
        for (int dt = 0; dt < 4; ++dt)
            vf[dt] = ld8(Vp + (size_t)(w * 64 + dt * 16 + r) * NT + n0 + q * 8);

        if (it + 1 < cnt) {
#pragma unroll
            for (int j = 0; j < 4; ++j)
                dma16(Kp + (size_t)(n0 + 32 + tt_d * 16 + r) * CD + ((cb_d + j) * 4 + q) * 8,
                      &Ks[1 - p][tt_d * 4096 + (cb_d + j) * 512]);
        }

        // QK swapped: S^T tiles; lane (r,q) reg i = S[row m0+w*16+r][tok n0+tt*16+q*4+i]
        floatx4 s0 = {0.f, 0.f, 0.f, 0.f};
        floatx4 s1 = {0.f, 0.f, 0.f, 0.f};
#pragma unroll
        for (int c = 0; c < 8; ++c) {
            s0 = mfma16(ld8(&Ks[p][c * 512 + l * 8]), qf[c], s0);
            s1 = mfma16(ld8(&Ks[p][4096 + c * 512 + l * 8]), qf[c], s1);
        }

        // exp + scalar lsum + packed b64 P writes (4 bf16 each)
#pragma unroll
        for (int tt = 0; tt < 2; ++tt) {
            floatx4 sv = tt ? s1 : s0;
            float e0 = __expf(sv[0]), e1 = __expf(sv[1]);
            float e2 = __expf(sv[2]), e3 = __expf(sv[3]);
            ls += (e0 + e1) + (e2 + e3);
            short4v pk;
            pk.x = bf16s(e0); pk.y = bf16s(e1); pk.z = bf16s(e2); pk.w = bf16s(e3);
            *(short4v*)&P[w * 16 + r][tt * 16 + q * 4] = pk;
        }
        // P visible block-wide; NOT __syncthreads (would drain the K DMA)
        asm volatile("s_waitcnt lgkmcnt(0)\n\ts_barrier" ::: "memory");

        // PV: o[rt][dt] += P[rt rows][tok] x V[d-slice][tok]
#pragma unroll
        for (int rt = 0; rt < 4; ++rt) {
            short8 pf = ld8(&P[rt * 16 + r][q * 8]);
#pragma unroll
            for (int dt = 0; dt < 4; ++dt)
                o[rt][dt] = mfma16(pf, vf[dt], o[rt][dt]);
        }
    }

    // partial lsum: lane (r,q) holds row m0+w*16+r partial; reduce across q
    ls += __shfl_xor(ls, 16);
    ls += __shfl_xor(ls, 32);
    if (l < 16)
        Lp[(size_t)ks * MTOT + b * NT + m0 + w * 16 + l] = ls;

    // unnormalized partial O store (cols w*64..+64, all 64 rows)
#pragma unroll
    for (int rt = 0; rt < 4; ++rt)
#pragma unroll
        for (int i = 0; i < 4; ++i) {
            int row = m0 + rt * 16 + q * 4 + i;
#pragma unroll
            for (int dt = 0; dt < 4; ++dt)
                Op[((size_t)b * NT + row) * CD + w * 64 + dt * 16 + r] =
                    bf16s(o[rt][dt][i]);
        }
}

// ---- output projection + split-K combine: A = (sum Opk)/(sum lk), fp32 out
__global__ __launch_bounds__(256) void k_oproj(const short* __restrict__ Op0,
                                               const short* __restrict__ Op1,
                                               const short* __restrict__ Op2,
                                               const float* __restrict__ Lp,
                                               const short* __restrict__ Wot,
                                               const float* __restrict__ bo,
                                               float* __restrict__ out, int nks) {
    __shared__ __align__(16) short Ws[16384];
    int m0 = blockIdx.x * 128;
    int n0 = blockIdx.y * 64;
    int tid = threadIdx.x;
    int w = tid >> 6, l = tid & 63, r = l & 15, q = l >> 4;

#pragma unroll
    for (int cg = 0; cg < 8; ++cg)
        dma16(Wot + (size_t)(n0 + w * 16 + r) * CD + (cg * 4 + q) * 8,
              &Ws[w * 4096 + cg * 512]);
    __syncthreads();

    int row0 = m0 + w * 32 + r;
    float lt0 = Lp[row0] + Lp[MTOT + row0];
    float lt1 = Lp[row0 + 16] + Lp[MTOT + row0 + 16];
    if (nks == 3) { lt0 += Lp[2 * MTOT + row0]; lt1 += Lp[2 * MTOT + row0 + 16]; }
    float inv0 = 1.0f / lt0, inv1 = 1.0f / lt1;
    const short* p00 = Op0 + (size_t)row0 * CD;
    const short* p01 = Op1 + (size_t)row0 * CD;
    const short* p02 = Op2 + (size_t)row0 * CD;
    floatx4 acc[2][4];
#pragma unroll
    for (int rt = 0; rt < 2; ++rt)
#pragma unroll
        for (int j = 0; j < 4; ++j) acc[rt][j] = (floatx4){0.f, 0.f, 0.f, 0.f};
#pragma unroll
    for (int c = 0; c < 8; ++c) {
        int off0 = c * 32 + q * 8, off1 = 16 * CD + c * 32 + q * 8;
        short8 x0 = ld8(p00 + off0), y0 = ld8(p01 + off0);
        short8 x1 = ld8(p00 + off1), y1 = ld8(p01 + off1);
        short8 af0, af1;
        if (nks == 3) {
            short8 z0 = ld8(p02 + off0), z1 = ld8(p02 + off1);
#pragma unroll
            for (int jj = 0; jj < 8; ++jj) {
                af0[jj] = bf16s((bf2f(x0[jj]) + bf2f(y0[jj]) + bf2f(z0[jj])) * inv0);
                af1[jj] = bf16s((bf2f(x1[jj]) + bf2f(y1[jj]) + bf2f(z1[jj])) * inv1);
            }
        } else {
#pragma unroll
            for (int jj = 0; jj < 8; ++jj) {
                af0[jj] = bf16s((bf2f(x0[jj]) + bf2f(y0[jj])) * inv0);
                af1[jj] = bf16s((bf2f(x1[jj]) + bf2f(y1[jj])) * inv1);
            }
        }
#pragma unroll
        for (int j = 0; j < 4; ++j) {
            short8 wf = ld8(&Ws[j * 4096 + c * 512 + l * 8]);
            acc[0][j] = mfma16(af0, wf, acc[0][j]);
            acc[1][j] = mfma16(af1, wf, acc[1][j]);
        }
    }
#pragma unroll
    for (int rt = 0; rt < 2; ++rt)
#pragma unroll
        for (int j = 0; j < 4; ++j) {
            int col = n0 + j * 16 + r;
            float bvv = bo[col];
#pragma unroll
            for (int i = 0; i < 4; ++i)
                out[(size_t)(m0 + w * 32 + rt * 16 + q * 4 + i) * CD + col] =
                    acc[rt][j][i] + bvv;
        }
}

extern "C" void kernel_launch(void* const* d_in, const int* in_sizes, int n_in,
                              void* d_out, int out_size, void* d_ws, size_t ws_size,
                              hipStream_t stream) {
    const float* x  = (const float*)d_in[0];
    const float* Wq = (const float*)d_in[1];
    const float* bq = (const float*)d_in[2];
    const float* Wk = (const float*)d_in[3];
    const float* bk = (const float*)d_in[4];
    const float* Wv = (const float*)d_in[5];
    const float* bv = (const float*)d_in[6];
    const float* Wo = (const float*)d_in[7];
    const float* bo = (const float*)d_in[8];
    float* out = (float*)d_out;

    char* ws = (char*)d_ws;
    const size_t MB = 1024u * 1024u;
    short* xb  = (short*)(ws);             // 8 MB: x bf16; DEAD after proj3 ->
    short* Op0 = (short*)(ws);             //        reused as partial-O (ks=0)
    short* Qb  = (short*)(ws + 8 * MB);    // 8 MB: Q*scale bf16
    short* Kb  = (short*)(ws + 16 * MB);   // 8 MB: K bf16
    short* Vt  = (short*)(ws + 24 * MB);   // 8 MB: V^T bf16 [4][256][4096]
    short* Op1 = (short*)(ws + 32 * MB);   // 8 MB: partial-O (ks=1)
    short* Wt  = (short*)(ws + 40 * MB);   // 512 KB: transposed weights bf16
    float* Lp  = (float*)(ws + 40 * MB + 512 * 1024);  // 192 KB: partial l [3][16384]
    short* Op2 = (short*)(ws + 41 * MB);   // 8 MB: partial-O (ks=2), if ws allows

    // 3-way split-K (768 blocks = 3/CU) when workspace permits, else 2-way.
    int nks = (ws_size >= 49 * MB + 512 * 1024) ? 3 : 2;
    if (nks == 2) Op2 = Op1;   // unused, keep pointer valid

    k_convx<<<dim3(MTOT * CD / (256 * 4)), 256, 0, stream>>>(x, xb);
    k_convw<<<dim3(256, 4), 256, 0, stream>>>(Wq, Wk, Wv, Wo, Wt);
    k_proj3<<<dim3(MTOT / 128, CD / 64, 3), 256, 0, stream>>>(xb, Wt, bq, bk, bv, Qb, Kb, Vt);
    k_attn<<<dim3(NT / 64, NB, nks), 256, 0, stream>>>(Qb, Kb, Vt, Op0, Op1, Op2, Lp, nks);
    k_oproj<<<dim3(MTOT / 128, CD / 64), 256, 0, stream>>>(Op0, Op1, Op2, Lp, Wt + 196608, bo, out, nks);
}